// Round 1
// baseline (14191.849 us; speedup 1.0000x reference)
//
#include <hip/hip_runtime.h>
#include <math.h>

// Problem constants (from reference)
#define BATCH 256
#define TSEQ  512
#define FEAT  64
#define NU1   256
#define NG1   768   // 3*NU1
#define NU2   128
#define NG2   384   // 3*NU2
#define ROWS  2     // batch rows per workgroup -> 128 WGs

__device__ __forceinline__ float sigmoid_f(float v) {
    return 1.0f / (1.0f + __expf(-v));
}

__device__ __forceinline__ float tanh_f(float v) {
    // (e^{2v}-1)/(e^{2v}+1), clamped to avoid inf/inf
    float c = fminf(fmaxf(v, -15.0f), 15.0f);
    float e = __expf(2.0f * c);
    return (e - 1.0f) / (e + 1.0f);
}

// One workgroup handles ROWS batch rows through both GRU layers for all T
// steps, then the dense head. Thread j owns gate-column triple
// (j, U+j, 2U+j) of each GRU; input projections computed on the fly.
__global__ __launch_bounds__(256, 1)
void gru_fused_kernel(const float* __restrict__ x,
                      const float* __restrict__ k1, const float* __restrict__ r1,
                      const float* __restrict__ b1,
                      const float* __restrict__ k2, const float* __restrict__ r2,
                      const float* __restrict__ b2,
                      const float* __restrict__ w3, const float* __restrict__ b3,
                      const float* __restrict__ w4, const float* __restrict__ b4,
                      const float* __restrict__ w5, const float* __restrict__ b5,
                      float* __restrict__ out)
{
    const int tid  = threadIdx.x;
    const int row0 = blockIdx.x * ROWS;   // first batch row of this WG

    __shared__ float h1[ROWS][NU1];
    __shared__ float h2[ROWS][NU2];
    __shared__ float xt[2][ROWS][FEAT];   // double-buffered x_t
    __shared__ float d3[ROWS][64];
    __shared__ float d4[ROWS][32];

    // zero-init hidden state (harness poisons nothing we rely on, but be safe)
    for (int i = tid; i < ROWS * NU1; i += 256) (&h1[0][0])[i] = 0.0f;
    for (int i = tid; i < ROWS * NU2; i += 256) (&h2[0][0])[i] = 0.0f;

    const int j = tid;
    // GRU1 bias folding: z,r get (input bias + recurrent bias); h keeps them
    // separate because the recurrent part is multiplied by r (reset_after).
    const float bz1  = b1[j]           + b1[NG1 + j];
    const float br1  = b1[NU1 + j]     + b1[NG1 + NU1 + j];
    const float bxh1 = b1[2 * NU1 + j];
    const float brh1 = b1[NG1 + 2 * NU1 + j];

    float bz2 = 0.0f, br2 = 0.0f, bxh2 = 0.0f, brh2 = 0.0f;
    if (j < NU2) {
        bz2  = b2[j]           + b2[NG2 + j];
        br2  = b2[NU2 + j]     + b2[NG2 + NU2 + j];
        bxh2 = b2[2 * NU2 + j];
        brh2 = b2[NG2 + 2 * NU2 + j];
    }

    // preload x at t=0
    const int pr = tid >> 6;        // tid / FEAT
    const int pf = tid & (FEAT - 1);
    if (tid < ROWS * FEAT) {
        xt[0][pr][pf] = x[((size_t)(row0 + pr) * TSEQ + 0) * FEAT + pf];
    }
    __syncthreads();

    for (int t = 0; t < TSEQ; ++t) {
        const int cur = t & 1, nxt = cur ^ 1;

        // issue next-step x load early; waited on only at the LDS store below
        float xpre = 0.0f;
        if (t + 1 < TSEQ && tid < ROWS * FEAT) {
            xpre = x[((size_t)(row0 + pr) * TSEQ + (t + 1)) * FEAT + pf];
        }

        // ---------------- GRU1 ----------------
        float az[ROWS], ar[ROWS], axh[ROWS], arh[ROWS];
        #pragma unroll
        for (int r = 0; r < ROWS; ++r) { az[r] = bz1; ar[r] = br1; axh[r] = bxh1; arh[r] = brh1; }

        #pragma unroll 4
        for (int f = 0; f < FEAT; ++f) {
            const float wz = k1[f * NG1 + j];
            const float wr = k1[f * NG1 + NU1 + j];
            const float wh = k1[f * NG1 + 2 * NU1 + j];
            #pragma unroll
            for (int r = 0; r < ROWS; ++r) {
                const float xv = xt[cur][r][f];
                az[r]  += xv * wz;
                ar[r]  += xv * wr;
                axh[r] += xv * wh;
            }
        }
        #pragma unroll 4
        for (int u = 0; u < NU1; ++u) {
            const float wz = r1[u * NG1 + j];
            const float wr = r1[u * NG1 + NU1 + j];
            const float wh = r1[u * NG1 + 2 * NU1 + j];
            #pragma unroll
            for (int r = 0; r < ROWS; ++r) {
                const float hv = h1[r][u];
                az[r]  += hv * wz;
                ar[r]  += hv * wr;
                arh[r] += hv * wh;
            }
        }
        float hn1[ROWS];
        #pragma unroll
        for (int r = 0; r < ROWS; ++r) {
            const float z  = sigmoid_f(az[r]);
            const float rg = sigmoid_f(ar[r]);
            const float hh = tanh_f(axh[r] + rg * arh[r]);
            hn1[r] = z * h1[r][j] + (1.0f - z) * hh;
        }
        __syncthreads();   // all reads of old h1 done
        #pragma unroll
        for (int r = 0; r < ROWS; ++r) h1[r][j] = hn1[r];
        if (t + 1 < TSEQ && tid < ROWS * FEAT) xt[nxt][pr][pf] = xpre;
        __syncthreads();   // new h1 (layer-2 input) visible

        // ---------------- GRU2 (threads 0..127) ----------------
        float hn2[ROWS];
        if (j < NU2) {
            float az2[ROWS], ar2[ROWS], axh2[ROWS], arh2[ROWS];
            #pragma unroll
            for (int r = 0; r < ROWS; ++r) { az2[r] = bz2; ar2[r] = br2; axh2[r] = bxh2; arh2[r] = brh2; }

            #pragma unroll 4
            for (int u = 0; u < NU1; ++u) {
                const float wz = k2[u * NG2 + j];
                const float wr = k2[u * NG2 + NU2 + j];
                const float wh = k2[u * NG2 + 2 * NU2 + j];
                #pragma unroll
                for (int r = 0; r < ROWS; ++r) {
                    const float hv = h1[r][u];
                    az2[r]  += hv * wz;
                    ar2[r]  += hv * wr;
                    axh2[r] += hv * wh;
                }
            }
            #pragma unroll 4
            for (int u = 0; u < NU2; ++u) {
                const float wz = r2[u * NG2 + j];
                const float wr = r2[u * NG2 + NU2 + j];
                const float wh = r2[u * NG2 + 2 * NU2 + j];
                #pragma unroll
                for (int r = 0; r < ROWS; ++r) {
                    const float hv = h2[r][u];
                    az2[r]  += hv * wz;
                    ar2[r]  += hv * wr;
                    arh2[r] += hv * wh;
                }
            }
            #pragma unroll
            for (int r = 0; r < ROWS; ++r) {
                const float z  = sigmoid_f(az2[r]);
                const float rg = sigmoid_f(ar2[r]);
                const float hh = tanh_f(axh2[r] + rg * arh2[r]);
                hn2[r] = z * h2[r][j] + (1.0f - z) * hh;
            }
        }
        __syncthreads();   // all reads of old h2 done
        if (j < NU2) {
            #pragma unroll
            for (int r = 0; r < ROWS; ++r) h2[r][j] = hn2[r];
        }
        __syncthreads();
    }

    // ---------------- dense head: h2 -> 64 -> 32 -> 24 ----------------
    if (tid < ROWS * 64) {
        const int r = tid >> 6, jj = tid & 63;
        float a = b3[jj];
        #pragma unroll 4
        for (int u = 0; u < NU2; ++u) a += h2[r][u] * w3[u * 64 + jj];
        d3[r][jj] = a;
    }
    __syncthreads();
    if (tid < ROWS * 32) {
        const int r = tid >> 5, jj = tid & 31;
        float a = b4[jj];
        #pragma unroll 4
        for (int u = 0; u < 64; ++u) a += d3[r][u] * w4[u * 32 + jj];
        d4[r][jj] = a;
    }
    __syncthreads();
    if (tid < ROWS * 32) {
        const int r = tid >> 5, jj = tid & 31;
        if (jj < 24) {
            float a = b5[jj];
            #pragma unroll 4
            for (int u = 0; u < 32; ++u) a += d4[r][u] * w5[u * 24 + jj];
            out[(size_t)(row0 + r) * 24 + jj] = a;
        }
    }
}

extern "C" void kernel_launch(void* const* d_in, const int* in_sizes, int n_in,
                              void* d_out, int out_size, void* d_ws, size_t ws_size,
                              hipStream_t stream) {
    (void)in_sizes; (void)n_in; (void)d_ws; (void)ws_size; (void)out_size;
    const float* x  = (const float*)d_in[0];
    const float* k1 = (const float*)d_in[1];
    const float* r1 = (const float*)d_in[2];
    const float* b1 = (const float*)d_in[3];
    const float* k2 = (const float*)d_in[4];
    const float* r2 = (const float*)d_in[5];
    const float* b2 = (const float*)d_in[6];
    const float* w3 = (const float*)d_in[7];
    const float* b3 = (const float*)d_in[8];
    const float* w4 = (const float*)d_in[9];
    const float* b4 = (const float*)d_in[10];
    const float* w5 = (const float*)d_in[11];
    const float* b5 = (const float*)d_in[12];
    float* out = (float*)d_out;

    dim3 grid(BATCH / ROWS);
    dim3 block(256);
    hipLaunchKernelGGL(gru_fused_kernel, grid, block, 0, stream,
                       x, k1, r1, b1, k2, r2, b2, w3, b3, w4, b4, w5, b5, out);
}

// Round 2
// 8711.639 us; speedup vs baseline: 1.6291x; 1.6291x over previous
//
#include <hip/hip_runtime.h>
#include <hip/hip_fp16.h>
#include <math.h>

// Problem constants
#define BATCH 256
#define TSEQ  512
#define FEAT  64
#define NU1   256
#define NU2   128
#define ROWS  2      // batch rows per WG -> 128 WGs
#define BLK   8      // pairs per pipeline block (24 outstanding 4B loads)

// half2-element offsets inside workspace (packed fp16 weight planes)
// GRU1: 160 row-pairs (rows = k1 0..63 then r1 0..255) x 256 cols, per gate
// GRU2: 192 row-pairs (rows = k2 0..255 then r2 0..127) x 128 cols, per gate
#define G1Z_OFF 0
#define G1R_OFF 40960
#define G1H_OFF 81920
#define G2Z_OFF 122880
#define G2R_OFF 147456
#define G2H_OFF 172032
#define TOTAL_H2 196608   // 786,432 bytes of d_ws

__device__ __forceinline__ float sigmoid_f(float v) {
    return 1.0f / (1.0f + __expf(-v));
}
__device__ __forceinline__ float tanh_f(float v) {
    float c = fminf(fmaxf(v, -15.0f), 15.0f);
    float e = __expf(2.0f * c);
    return (e - 1.0f) / (e + 1.0f);
}

// ---------------- weight packing (fp32 -> fp16 planes) ----------------
__global__ void pack_weights(const float* __restrict__ k1, const float* __restrict__ r1,
                             const float* __restrict__ k2, const float* __restrict__ r2,
                             __half2* __restrict__ ws)
{
    int idx = blockIdx.x * 256 + threadIdx.x;
    if (idx >= TOTAL_H2) return;
    float a, b;
    if (idx < G2Z_OFF) {
        // GRU1 planes: 3 x [160 pairs][256 cols]
        int plane = idx / 40960;       // 0=z 1=r 2=h
        int rem   = idx % 40960;
        int pair  = rem >> 8;
        int col   = rem & 255;
        int g     = plane * 256 + col; // gate-column in [0,768)
        int row0  = pair * 2;
        if (row0 < 64) { a = k1[row0 * 768 + g];        b = k1[(row0 + 1) * 768 + g]; }
        else           { a = r1[(row0 - 64) * 768 + g]; b = r1[(row0 - 63) * 768 + g]; }
    } else {
        // GRU2 planes: 3 x [192 pairs][128 cols]
        int idx2  = idx - G2Z_OFF;
        int plane = idx2 / 24576;
        int rem   = idx2 % 24576;
        int pair  = rem >> 7;
        int col   = rem & 127;
        int g     = plane * 128 + col; // gate-column in [0,384)
        int row0  = pair * 2;
        if (row0 < 256) { a = k2[row0 * 384 + g];         b = k2[(row0 + 1) * 384 + g]; }
        else            { a = r2[(row0 - 256) * 384 + g]; b = r2[(row0 - 255) * 384 + g]; }
    }
    __half2 h;
    h.x = __float2half_rn(a);
    h.y = __float2half_rn(b);
    ws[idx] = h;
}

// acc += w.lo * x0 + w.hi * x1   (fp16 weight, fp32 data/accum; cvt is exact)
__device__ __forceinline__ void fma2(float& acc, __half2 w, float x0, float x1) {
    acc = fmaf(__half2float(__low2half(w)),  x0, acc);
    acc = fmaf(__half2float(__high2half(w)), x1, acc);
}

// Two-batch-row segment: pz/pr/ph point at (pair0, this thread's column);
// s0/s1 are the LDS input vectors for batch rows 0/1, indexed by 2*pair.
template <int STRIDE, int NPAIRS>
__device__ __forceinline__ void gru_seg2(const __half2* __restrict__ pz,
                                         const __half2* __restrict__ pr,
                                         const __half2* __restrict__ ph,
                                         const float* __restrict__ s0,
                                         const float* __restrict__ s1,
                                         float* az, float* ar, float* ah)
{
    constexpr int NB = NPAIRS / BLK;
    __half2 bz[2][BLK], br[2][BLK], bh[2][BLK];
    #pragma unroll
    for (int q = 0; q < BLK; ++q) {
        bz[0][q] = pz[q * STRIDE]; br[0][q] = pr[q * STRIDE]; bh[0][q] = ph[q * STRIDE];
    }
    #pragma unroll 2
    for (int b = 0; b < NB; ++b) {
        const int cur = b & 1, nxt = cur ^ 1;
        if (b + 1 < NB) {
            const __half2* z2 = pz + (b + 1) * BLK * STRIDE;
            const __half2* r2 = pr + (b + 1) * BLK * STRIDE;
            const __half2* h2 = ph + (b + 1) * BLK * STRIDE;
            #pragma unroll
            for (int q = 0; q < BLK; ++q) {
                bz[nxt][q] = z2[q * STRIDE]; br[nxt][q] = r2[q * STRIDE]; bh[nxt][q] = h2[q * STRIDE];
            }
        }
        #pragma unroll
        for (int q = 0; q < BLK; ++q) {
            const int i0 = (b * BLK + q) * 2;
            const float2 v0 = *(const float2*)(s0 + i0);
            const float2 v1 = *(const float2*)(s1 + i0);
            fma2(az[0], bz[cur][q], v0.x, v0.y); fma2(az[1], bz[cur][q], v1.x, v1.y);
            fma2(ar[0], br[cur][q], v0.x, v0.y); fma2(ar[1], br[cur][q], v1.x, v1.y);
            fma2(ah[0], bh[cur][q], v0.x, v0.y); fma2(ah[1], bh[cur][q], v1.x, v1.y);
        }
    }
}

// Single-row segment (GRU2: each thread handles one batch row)
template <int STRIDE, int NPAIRS>
__device__ __forceinline__ void gru_seg1(const __half2* __restrict__ pz,
                                         const __half2* __restrict__ pr,
                                         const __half2* __restrict__ ph,
                                         const float* __restrict__ s0,
                                         float* az, float* ar, float* ah)
{
    constexpr int NB = NPAIRS / BLK;
    __half2 bz[2][BLK], br[2][BLK], bh[2][BLK];
    #pragma unroll
    for (int q = 0; q < BLK; ++q) {
        bz[0][q] = pz[q * STRIDE]; br[0][q] = pr[q * STRIDE]; bh[0][q] = ph[q * STRIDE];
    }
    #pragma unroll 2
    for (int b = 0; b < NB; ++b) {
        const int cur = b & 1, nxt = cur ^ 1;
        if (b + 1 < NB) {
            const __half2* z2 = pz + (b + 1) * BLK * STRIDE;
            const __half2* r2 = pr + (b + 1) * BLK * STRIDE;
            const __half2* h2 = ph + (b + 1) * BLK * STRIDE;
            #pragma unroll
            for (int q = 0; q < BLK; ++q) {
                bz[nxt][q] = z2[q * STRIDE]; br[nxt][q] = r2[q * STRIDE]; bh[nxt][q] = h2[q * STRIDE];
            }
        }
        #pragma unroll
        for (int q = 0; q < BLK; ++q) {
            const int i0 = (b * BLK + q) * 2;
            const float2 v0 = *(const float2*)(s0 + i0);
            fma2(*az, bz[cur][q], v0.x, v0.y);
            fma2(*ar, br[cur][q], v0.x, v0.y);
            fma2(*ah, bh[cur][q], v0.x, v0.y);
        }
    }
}

__global__ __launch_bounds__(256, 1)
void gru_fused(const float* __restrict__ x,
               const float* __restrict__ b1, const float* __restrict__ b2,
               const float* __restrict__ w3, const float* __restrict__ b3,
               const float* __restrict__ w4, const float* __restrict__ b4,
               const float* __restrict__ w5, const float* __restrict__ b5,
               const __half2* __restrict__ wp,
               float* __restrict__ out)
{
    __shared__ float h1[ROWS][NU1];
    __shared__ float h2[ROWS][NU2];
    __shared__ float xt[2][ROWS][FEAT];
    __shared__ float d3[ROWS][64];
    __shared__ float d4[ROWS][32];

    const int tid  = threadIdx.x;
    const int row0 = blockIdx.x * ROWS;
    const int j    = tid;           // GRU1 unit owned by this thread
    const int u2   = tid & 127;     // GRU2 unit
    const int rr   = tid >> 7;      // GRU2 batch row

    for (int i = tid; i < ROWS * NU1; i += 256) (&h1[0][0])[i] = 0.0f;
    for (int i = tid; i < ROWS * NU2; i += 256) (&h2[0][0])[i] = 0.0f;

    // folded biases (gate order z,r,h; reset_after keeps h biases separate)
    const float bz1  = b1[j] + b1[768 + j];
    const float br1  = b1[256 + j] + b1[1024 + j];
    const float bxh1 = b1[512 + j];
    const float brh1 = b1[1280 + j];
    const float bz2  = b2[u2] + b2[384 + u2];
    const float br2  = b2[128 + u2] + b2[512 + u2];
    const float bxh2 = b2[256 + u2];
    const float brh2 = b2[640 + u2];

    const __half2* g1z = wp + G1Z_OFF + j;
    const __half2* g1r = wp + G1R_OFF + j;
    const __half2* g1h = wp + G1H_OFF + j;
    const __half2* g2z = wp + G2Z_OFF + u2;
    const __half2* g2r = wp + G2R_OFF + u2;
    const __half2* g2h = wp + G2H_OFF + u2;

    const int pr_ = tid >> 6, pf = tid & 63;
    if (tid < ROWS * FEAT)
        xt[0][pr_][pf] = x[((size_t)(row0 + pr_) * TSEQ) * FEAT + pf];
    __syncthreads();

    for (int t = 0; t < TSEQ; ++t) {
        const int cur = t & 1, nxt = cur ^ 1;

        float xpre = 0.0f;
        if (t + 1 < TSEQ && tid < ROWS * FEAT)
            xpre = x[((size_t)(row0 + pr_) * TSEQ + (t + 1)) * FEAT + pf];

        // ---------------- GRU1 ----------------
        float az[2]  = {bz1, bz1},  ar[2]  = {br1, br1};
        float axh[2] = {bxh1, bxh1}, arh[2] = {brh1, brh1};
        // x-part: pairs 0..31 (k1 rows), multiplier = x_t
        gru_seg2<256, 32>(g1z, g1r, g1h, &xt[cur][0][0], &xt[cur][1][0], az, ar, axh);
        // h-part: pairs 32..159 (r1 rows), multiplier = h1
        gru_seg2<256, 128>(g1z + 32 * 256, g1r + 32 * 256, g1h + 32 * 256,
                           &h1[0][0], &h1[1][0], az, ar, arh);

        float hn1[2];
        #pragma unroll
        for (int r = 0; r < 2; ++r) {
            const float z  = sigmoid_f(az[r]);
            const float rg = sigmoid_f(ar[r]);
            const float hh = tanh_f(axh[r] + rg * arh[r]);
            hn1[r] = z * h1[r][j] + (1.0f - z) * hh;
        }
        __syncthreads();                 // reads of old h1 complete
        h1[0][j] = hn1[0];
        h1[1][j] = hn1[1];
        if (t + 1 < TSEQ && tid < ROWS * FEAT) xt[nxt][pr_][pf] = xpre;
        __syncthreads();                 // new h1 + next x visible

        // ---------------- GRU2 (all 256 threads: row=rr, unit=u2) ----------------
        float az2 = bz2, ar2 = br2, axh2 = bxh2, arh2 = brh2;
        gru_seg1<128, 128>(g2z, g2r, g2h, &h1[rr][0], &az2, &ar2, &axh2);
        gru_seg1<128, 64>(g2z + 128 * 128, g2r + 128 * 128, g2h + 128 * 128,
                          &h2[rr][0], &az2, &ar2, &arh2);
        const float z2v = sigmoid_f(az2);
        const float rg2 = sigmoid_f(ar2);
        const float hh2 = tanh_f(axh2 + rg2 * arh2);
        const float hn2 = z2v * h2[rr][u2] + (1.0f - z2v) * hh2;
        __syncthreads();                 // reads of old h2 complete
        h2[rr][u2] = hn2;
        __syncthreads();
    }

    // ---------------- dense head: h2 -> 64 -> 32 -> 24 ----------------
    if (tid < ROWS * 64) {
        const int r = tid >> 6, jj = tid & 63;
        float a = b3[jj];
        #pragma unroll 4
        for (int u = 0; u < NU2; ++u) a += h2[r][u] * w3[u * 64 + jj];
        d3[r][jj] = a;
    }
    __syncthreads();
    if (tid < ROWS * 32) {
        const int r = tid >> 5, jj = tid & 31;
        float a = b4[jj];
        #pragma unroll 4
        for (int u = 0; u < 64; ++u) a += d3[r][u] * w4[u * 32 + jj];
        d4[r][jj] = a;
    }
    __syncthreads();
    if (tid < ROWS * 32) {
        const int r = tid >> 5, jj = tid & 31;
        if (jj < 24) {
            float a = b5[jj];
            #pragma unroll 4
            for (int u = 0; u < 32; ++u) a += d4[r][u] * w5[u * 24 + jj];
            out[(size_t)(row0 + r) * 24 + jj] = a;
        }
    }
}

extern "C" void kernel_launch(void* const* d_in, const int* in_sizes, int n_in,
                              void* d_out, int out_size, void* d_ws, size_t ws_size,
                              hipStream_t stream) {
    (void)in_sizes; (void)n_in; (void)ws_size; (void)out_size;
    const float* x  = (const float*)d_in[0];
    const float* k1 = (const float*)d_in[1];
    const float* r1 = (const float*)d_in[2];
    const float* b1 = (const float*)d_in[3];
    const float* k2 = (const float*)d_in[4];
    const float* r2 = (const float*)d_in[5];
    const float* b2 = (const float*)d_in[6];
    const float* w3 = (const float*)d_in[7];
    const float* b3 = (const float*)d_in[8];
    const float* w4 = (const float*)d_in[9];
    const float* b4 = (const float*)d_in[10];
    const float* w5 = (const float*)d_in[11];
    const float* b5 = (const float*)d_in[12];
    float* out = (float*)d_out;
    __half2* wp = (__half2*)d_ws;

    hipLaunchKernelGGL(pack_weights, dim3((TOTAL_H2 + 255) / 256), dim3(256), 0, stream,
                       k1, r1, k2, r2, wp);
    hipLaunchKernelGGL(gru_fused, dim3(BATCH / ROWS), dim3(256), 0, stream,
                       x, b1, b2, w3, b3, w4, b4, w5, b5, wp, out);
}